// Round 1
// baseline (155.135 us; speedup 1.0000x reference)
//
#include <hip/hip_runtime.h>

#define BB 4
#define HH 480
#define WW 640

// One Jacobi rotation on the (P,Q) plane of symmetric 4x4 A, accumulating
// the rotation into V. Template params keep all array indices compile-time
// constant so A/V live entirely in VGPRs.
template <int P, int Q>
__device__ __forceinline__ void jrot(float A[4][4], float V[4][4]) {
    float apq = A[P][Q];
    if (fabsf(apq) > 1e-12f) {
        float app = A[P][P], aqq = A[Q][Q];
        float tau = (aqq - app) * __builtin_amdgcn_rcpf(2.0f * apq);
        float t = __builtin_amdgcn_rcpf(fabsf(tau) + sqrtf(tau * tau + 1.0f));
        t = (tau >= 0.0f) ? t : -t;
        float c = __builtin_amdgcn_rsqf(t * t + 1.0f);
        float s = t * c;
        A[P][P] = app - t * apq;
        A[Q][Q] = aqq + t * apq;
        A[P][Q] = 0.0f;
        A[Q][P] = 0.0f;
#pragma unroll
        for (int k = 0; k < 4; ++k) {
            if (k == P || k == Q) continue;
            float akp = A[k][P], akq = A[k][Q];
            float rp = c * akp - s * akq;
            float rq = s * akp + c * akq;
            A[k][P] = rp; A[P][k] = rp;
            A[k][Q] = rq; A[Q][k] = rq;
        }
#pragma unroll
        for (int k = 0; k < 4; ++k) {
            float vkp = V[k][P], vkq = V[k][Q];
            V[k][P] = c * vkp - s * vkq;
            V[k][Q] = s * vkp + c * vkq;
        }
    }
}

__global__ __launch_bounds__(256) void d2n_kernel(const float* __restrict__ pts,
                                                  float* __restrict__ out) {
    int idx = blockIdx.x * 256 + threadIdx.x;
    if (idx >= BB * HH * WW) return;
    int x = idx % WW;
    int t1 = idx / WW;
    int y = t1 % HH;
    int b = t1 / HH;

    const size_t HW = (size_t)HH * WW;
    const float* xs = pts + ((size_t)b * 3 + 0) * HW;
    const float* ys = pts + ((size_t)b * 3 + 1) * HW;
    const float* zs = pts + ((size_t)b * 3 + 2) * HW;

    // Accumulate AtA (10 unique entries) over valid 3x3 neighbors.
    float sxx = 0.f, sxy = 0.f, sxz = 0.f, sx = 0.f;
    float syy = 0.f, syz = 0.f, sy = 0.f;
    float szz = 0.f, sz = 0.f, cnt = 0.f;
#pragma unroll
    for (int dy = -1; dy <= 1; ++dy) {
#pragma unroll
        for (int dx = -1; dx <= 1; ++dx) {
            int yy = y + dy, xx = x + dx;
            if (yy < 0 || yy >= HH || xx < 0 || xx >= WW) continue;
            int o = yy * WW + xx;
            float pz = zs[o];
            if (pz > 0.0f && pz < 10.0f) {
                float px = xs[o], py = ys[o];
                sxx += px * px; sxy += px * py; sxz += px * pz; sx += px;
                syy += py * py; syz += py * pz; sy += py;
                szz += pz * pz; sz += pz;
                cnt += 1.0f;
            }
        }
    }

    float A[4][4] = {{sxx, sxy, sxz, sx},
                     {sxy, syy, syz, sy},
                     {sxz, syz, szz, sz},
                     {sx,  sy,  sz,  cnt}};
    float V[4][4] = {{1, 0, 0, 0}, {0, 1, 0, 0}, {0, 0, 1, 0}, {0, 0, 0, 1}};

#pragma unroll 1
    for (int sweep = 0; sweep < 6; ++sweep) {
        jrot<0, 1>(A, V);
        jrot<0, 2>(A, V);
        jrot<0, 3>(A, V);
        jrot<1, 2>(A, V);
        jrot<1, 3>(A, V);
        jrot<2, 3>(A, V);
    }

    // Select eigenvector of the smallest eigenvalue (cndmask chain).
    float lm = A[0][0];
    float nx = V[0][0], ny = V[1][0], nz = V[2][0];
#pragma unroll
    for (int j = 1; j < 4; ++j) {
        if (A[j][j] < lm) {
            lm = A[j][j];
            nx = V[0][j]; ny = V[1][j]; nz = V[2][j];
        }
    }

    float nrm = sqrtf(nx * nx + ny * ny + nz * nz);
    float inv = __builtin_amdgcn_rcpf(fmaxf(nrm, 1e-12f));
    nx *= inv; ny *= inv; nz *= inv;

    int o = y * WW + x;
    float cx = xs[o], cy = ys[o], cz = zs[o];
    float dot = nx * cx + ny * cy + nz * cz;
    float sgn = (dot > 0.0f) ? 1.0f : ((dot < 0.0f) ? -1.0f : 0.0f);
    nx *= sgn; ny *= sgn; nz *= sgn;

    out[((size_t)b * 3 + 0) * HW + o] = nx;
    out[((size_t)b * 3 + 1) * HW + o] = ny;
    out[((size_t)b * 3 + 2) * HW + o] = nz;

    bool cvalid = (cz > 0.0f && cz < 10.0f);
    bool m = cvalid && (cnt >= 4.0f) && (nx * nx + ny * ny + nz * nz > 0.25f);
    out[(size_t)BB * 3 * HW + (size_t)b * HW + o] = m ? 1.0f : 0.0f;
}

extern "C" void kernel_launch(void* const* d_in, const int* in_sizes, int n_in,
                              void* d_out, int out_size, void* d_ws, size_t ws_size,
                              hipStream_t stream) {
    const float* pts = (const float*)d_in[0];
    float* out = (float*)d_out;
    int total = BB * HH * WW;
    d2n_kernel<<<(total + 255) / 256, 256, 0, stream>>>(pts, out);
}

// Round 2
// 94.119 us; speedup vs baseline: 1.6483x; 1.6483x over previous
//
#include <hip/hip_runtime.h>

#define BB 4
#define HH 480
#define WW 640

__device__ __forceinline__ float det3(float a, float b, float c,
                                      float d, float e, float f,
                                      float g, float h, float i) {
    return a * (e * i - f * h) - b * (d * i - f * g) + c * (d * h - e * g);
}

__global__ __launch_bounds__(256) void d2n_kernel(const float* __restrict__ pts,
                                                  float* __restrict__ out) {
    int idx = blockIdx.x * 256 + threadIdx.x;
    if (idx >= BB * HH * WW) return;
    int x = idx % WW;
    int t1 = idx / WW;
    int y = t1 % HH;
    int b = t1 / HH;

    const size_t HW = (size_t)HH * WW;
    const float* xs = pts + ((size_t)b * 3 + 0) * HW;
    const float* ys = pts + ((size_t)b * 3 + 1) * HW;
    const float* zs = pts + ((size_t)b * 3 + 2) * HW;

    // ---- Gram accumulation: 10 unique entries of AtA over valid 3x3 nbhd ----
    float sxx = 0.f, sxy = 0.f, sxz = 0.f, sx = 0.f;
    float syy = 0.f, syz = 0.f, sy = 0.f;
    float szz = 0.f, sz = 0.f, cnt = 0.f;
#pragma unroll
    for (int dy = -1; dy <= 1; ++dy) {
#pragma unroll
        for (int dx = -1; dx <= 1; ++dx) {
            int yy = y + dy, xx = x + dx;
            if (yy < 0 || yy >= HH || xx < 0 || xx >= WW) continue;
            int o = yy * WW + xx;
            float pz = zs[o];
            if (pz > 0.0f && pz < 10.0f) {
                float px = xs[o], py = ys[o];
                sxx += px * px; sxy += px * py; sxz += px * pz; sx += px;
                syy += py * py; syz += py * pz; sy += py;
                szz += pz * pz; sz += pz;
                cnt += 1.0f;
            }
        }
    }

    // ---- Scale by 1/trace: eigenvalues land in [0,1], trace(M)=1 ----
    float tr = sxx + syy + szz + cnt;
    float it = __builtin_amdgcn_rcpf(tr);
    float m00 = sxx * it, m01 = sxy * it, m02 = sxz * it, m03 = sx * it;
    float m11 = syy * it, m12 = syz * it, m13 = sy * it;
    float m22 = szz * it, m23 = sz * it, m33 = cnt * it;

    // ---- Characteristic polynomial p(l) = l^4 - e1 l^3 + e2 l^2 - e3 l + e4 ----
    float e1 = m00 + m11 + m22 + m33;  // ~1.0 after scaling
    float e2 = (m00 * m11 - m01 * m01) + (m00 * m22 - m02 * m02) +
               (m00 * m33 - m03 * m03) + (m11 * m22 - m12 * m12) +
               (m11 * m33 - m13 * m13) + (m22 * m33 - m23 * m23);
    float P0 = det3(m11, m12, m13, m12, m22, m23, m13, m23, m33);
    float P1 = det3(m00, m02, m03, m02, m22, m23, m03, m23, m33);
    float P2 = det3(m00, m01, m03, m01, m11, m13, m03, m13, m33);
    float P3 = det3(m00, m01, m02, m01, m11, m12, m02, m12, m22);
    float e3 = P0 + P1 + P2 + P3;
    // det(M): row-0 cofactor expansion (signs folded in)
    float e4 = m00 * P0
             - m01 * det3(m01, m12, m13, m02, m22, m23, m03, m23, m33)
             + m02 * det3(m01, m11, m13, m02, m12, m23, m03, m13, m33)
             - m03 * det3(m01, m11, m12, m02, m12, m22, m03, m13, m23);

    // ---- Newton from 0 toward smallest eigenvalue (monotone: p>0, p'<0) ----
    float lam = 0.0f;
#pragma unroll
    for (int itn = 0; itn < 16; ++itn) {
        float p  = (((lam - e1) * lam + e2) * lam - e3) * lam + e4;
        float dp = ((4.0f * lam - 3.0f * e1) * lam + 2.0f * e2) * lam - e3;
        dp = fminf(dp, -1e-30f);  // strictly negative left of the root
        lam = lam - p * __builtin_amdgcn_rcpf(dp);
        lam = fminf(fmaxf(lam, 0.0f), 0.26f);  // mu1 <= trace/4 = 0.25
    }

    // ---- Eigenvector: column of adj(M - lam I) with largest diagonal ----
    float n00 = m00 - lam, n11 = m11 - lam, n22 = m22 - lam, n33 = m33 - lam;
    float n01 = m01, n02 = m02, n03 = m03, n12 = m12, n13 = m13, n23 = m23;

    float C00 =  det3(n11, n12, n13, n12, n22, n23, n13, n23, n33);
    float C01 = -det3(n01, n12, n13, n02, n22, n23, n03, n23, n33);
    float C02 =  det3(n01, n11, n13, n02, n12, n23, n03, n13, n33);
    float C03 = -det3(n01, n11, n12, n02, n12, n22, n03, n13, n23);
    float C11 =  det3(n00, n02, n03, n02, n22, n23, n03, n23, n33);
    float C12 = -det3(n00, n01, n03, n02, n12, n23, n03, n13, n33);
    float C13 =  det3(n00, n01, n02, n02, n12, n22, n03, n13, n23);
    float C22 =  det3(n00, n01, n03, n01, n11, n13, n03, n13, n33);
    float C23 = -det3(n00, n01, n02, n01, n11, n12, n03, n13, n23);
    float C33 =  det3(n00, n01, n02, n01, n11, n12, n02, n12, n22);

    // columns of adj (symmetric): pick by largest |diagonal cofactor|
    float best = fabsf(C00);
    float vx = C00, vy = C01, vz = C02;
    float a1 = fabsf(C11);
    if (a1 > best) { best = a1; vx = C01; vy = C11; vz = C12; }
    float a2 = fabsf(C22);
    if (a2 > best) { best = a2; vx = C02; vy = C12; vz = C22; }
    float a3 = fabsf(C33);
    if (a3 > best) { best = a3; vx = C03; vy = C13; vz = C23; }

    // ---- Normalize first 3 comps, sign-flip by center point ----
    float nrm = sqrtf(vx * vx + vy * vy + vz * vz);
    float inv = __builtin_amdgcn_rcpf(fmaxf(nrm, 1e-12f));
    float nx = vx * inv, ny = vy * inv, nz = vz * inv;

    int o = y * WW + x;
    float cx = xs[o], cy = ys[o], cz = zs[o];
    float dot = nx * cx + ny * cy + nz * cz;
    float sgn = (dot > 0.0f) ? 1.0f : ((dot < 0.0f) ? -1.0f : 0.0f);
    nx *= sgn; ny *= sgn; nz *= sgn;

    out[((size_t)b * 3 + 0) * HW + o] = nx;
    out[((size_t)b * 3 + 1) * HW + o] = ny;
    out[((size_t)b * 3 + 2) * HW + o] = nz;

    bool cvalid = (cz > 0.0f && cz < 10.0f);
    bool m = cvalid && (cnt >= 4.0f) && (nx * nx + ny * ny + nz * nz > 0.25f);
    out[(size_t)BB * 3 * HW + (size_t)b * HW + o] = m ? 1.0f : 0.0f;
}

extern "C" void kernel_launch(void* const* d_in, const int* in_sizes, int n_in,
                              void* d_out, int out_size, void* d_ws, size_t ws_size,
                              hipStream_t stream) {
    const float* pts = (const float*)d_in[0];
    float* out = (float*)d_out;
    int total = BB * HH * WW;
    d2n_kernel<<<(total + 255) / 256, 256, 0, stream>>>(pts, out);
}

// Round 4
// 93.572 us; speedup vs baseline: 1.6579x; 1.0058x over previous
//
#include <hip/hip_runtime.h>

#define BB 4
#define HH 480
#define WW 640

__device__ __forceinline__ double det3d(double a, double b, double c,
                                        double d, double e, double f,
                                        double g, double h, double i) {
    return a * (e * i - f * h) - b * (d * i - f * g) + c * (d * h - e * g);
}

__global__ __launch_bounds__(256) void d2n_kernel(const float* __restrict__ pts,
                                                  float* __restrict__ out) {
    int idx = blockIdx.x * 256 + threadIdx.x;
    if (idx >= BB * HH * WW) return;
    int x = idx % WW;
    int t1 = idx / WW;
    int y = t1 % HH;
    int b = t1 / HH;

    const size_t HW = (size_t)HH * WW;
    const float* xs = pts + ((size_t)b * 3 + 0) * HW;
    const float* ys = pts + ((size_t)b * 3 + 1) * HW;
    const float* zs = pts + ((size_t)b * 3 + 2) * HW;

    // ---- Branch-free stencil: clamped addresses, all 27 loads in flight ----
    float px[9], py[9], pz[9];
    bool inb[9];
#pragma unroll
    for (int i = 0; i < 9; ++i) {
        int dy = i / 3 - 1, dx = i % 3 - 1;
        int yy = y + dy, xx = x + dx;
        inb[i] = ((unsigned)yy < HH) & ((unsigned)xx < WW);
        int yyc = min(max(yy, 0), HH - 1);
        int xxc = min(max(xx, 0), WW - 1);
        int o = yyc * WW + xxc;
        pz[i] = zs[o];
        px[i] = xs[o];
        py[i] = ys[o];
    }

    // ---- Gram accumulation (f32, matches reference AtA precision) ----
    float sxx = 0.f, sxy = 0.f, sxz = 0.f, sx = 0.f;
    float syy = 0.f, syz = 0.f, sy = 0.f;
    float szz = 0.f, sz = 0.f, cnt = 0.f;
#pragma unroll
    for (int i = 0; i < 9; ++i) {
        float w = (inb[i] && pz[i] > 0.0f && pz[i] < 10.0f) ? 1.0f : 0.0f;
        float qx = px[i] * w, qy = py[i] * w, qz = pz[i] * w;
        sxx += qx * px[i]; sxy += qx * py[i]; sxz += qx * pz[i]; sx += qx;
        syy += qy * py[i]; syz += qy * pz[i]; sy += qy;
        szz += qz * pz[i]; sz += qz;
        cnt += w;
    }

    // ---- Promote to f64; scale by 1/trace so eigenvalues land in [0,1] ----
    double tr = (double)sxx + (double)syy + (double)szz + (double)cnt;
    double it = 1.0 / tr;
    double m00 = sxx * it, m01 = sxy * it, m02 = sxz * it, m03 = sx * it;
    double m11 = syy * it, m12 = syz * it, m13 = sy * it;
    double m22 = szz * it, m23 = sz * it, m33 = cnt * it;

    // ---- Characteristic polynomial p(l)=l^4 - e1 l^3 + e2 l^2 - e3 l + e4 ----
    double e1 = m00 + m11 + m22 + m33;
    double e2 = (m00 * m11 - m01 * m01) + (m00 * m22 - m02 * m02) +
                (m00 * m33 - m03 * m03) + (m11 * m22 - m12 * m12) +
                (m11 * m33 - m13 * m13) + (m22 * m33 - m23 * m23);
    double P0 = det3d(m11, m12, m13, m12, m22, m23, m13, m23, m33);
    double P1 = det3d(m00, m02, m03, m02, m22, m23, m03, m23, m33);
    double P2 = det3d(m00, m01, m03, m01, m11, m13, m03, m13, m33);
    double P3 = det3d(m00, m01, m02, m01, m11, m12, m02, m12, m22);
    double e3 = P0 + P1 + P2 + P3;
    double e4 = m00 * P0
              - m01 * det3d(m01, m12, m13, m02, m22, m23, m03, m23, m33)
              + m02 * det3d(m01, m11, m13, m02, m12, m23, m03, m13, m33)
              - m03 * det3d(m01, m11, m12, m02, m12, m22, m03, m13, m23);

    // ---- Newton from 0 toward smallest eigenvalue (monotone: p>0, p'<0) ----
    double lam = 0.0;
#pragma unroll
    for (int itn = 0; itn < 16; ++itn) {
        double p  = (((lam - e1) * lam + e2) * lam - e3) * lam + e4;
        double dp = ((4.0 * lam - 3.0 * e1) * lam + 2.0 * e2) * lam - e3;
        dp = fmin(dp, -1e-300);
        lam = lam - p / dp;
        lam = fmin(fmax(lam, 0.0), 0.26);
    }

    // ---- Adjugate of (M - lam I): rank-1 = c * v1 v1^T at converged lam ----
    double d0 = m00 - lam, d1 = m11 - lam, d2 = m22 - lam, d3 = m33 - lam;
    double C00 =  det3d(d1, m12, m13, m12, d2, m23, m13, m23, d3);
    double C01 = -det3d(m01, m12, m13, m02, d2, m23, m03, m23, d3);
    double C02 =  det3d(m01, d1, m13, m02, m12, m23, m03, m13, d3);
    double C03 = -det3d(m01, d1, m12, m02, m12, d2, m03, m13, m23);
    double C11 =  det3d(d0, m02, m03, m02, d2, m23, m03, m23, d3);
    double C12 = -det3d(d0, m01, m03, m02, m12, m23, m03, m13, d3);
    double C13 =  det3d(d0, m01, m02, m02, m12, d2, m03, m13, m23);
    double C22 =  det3d(d0, m01, m03, m01, d1, m13, m03, m13, d3);
    double C23 = -det3d(d0, m01, m02, m01, d1, m12, m03, m13, m23);
    double C33 =  det3d(d0, m01, m02, m01, d1, m12, m02, m12, d2);

    // pick column with largest |diagonal cofactor| (= largest v1 component^2)
    double best = fabs(C00);
    double vx = C00, vy = C01, vz = C02;
    double a1 = fabs(C11);
    if (a1 > best) { best = a1; vx = C01; vy = C11; vz = C12; }
    double a2 = fabs(C22);
    if (a2 > best) { best = a2; vx = C02; vy = C12; vz = C22; }
    double a3 = fabs(C33);
    if (a3 > best) { best = a3; vx = C03; vy = C13; vz = C23; }

    // ---- Normalize first 3 comps (f64), sign-flip by center point ----
    double nd = vx * vx + vy * vy + vz * vz;
    double inv = 1.0 / fmax(sqrt(nd), 1e-300);
    float nx = (float)(vx * inv), ny = (float)(vy * inv), nz = (float)(vz * inv);

    int o = y * WW + x;
    float cx = px[4], cy = py[4], cz = pz[4];
    float dot = nx * cx + ny * cy + nz * cz;
    float sgn = (dot > 0.0f) ? 1.0f : ((dot < 0.0f) ? -1.0f : 0.0f);
    nx *= sgn; ny *= sgn; nz *= sgn;

    out[((size_t)b * 3 + 0) * HW + o] = nx;
    out[((size_t)b * 3 + 1) * HW + o] = ny;
    out[((size_t)b * 3 + 2) * HW + o] = nz;

    bool cvalid = (cz > 0.0f && cz < 10.0f);
    bool m = cvalid && (cnt >= 4.0f) && (nx * nx + ny * ny + nz * nz > 0.25f);
    out[(size_t)BB * 3 * HW + (size_t)b * HW + o] = m ? 1.0f : 0.0f;
}

extern "C" void kernel_launch(void* const* d_in, const int* in_sizes, int n_in,
                              void* d_out, int out_size, void* d_ws, size_t ws_size,
                              hipStream_t stream) {
    const float* pts = (const float*)d_in[0];
    float* out = (float*)d_out;
    int total = BB * HH * WW;
    d2n_kernel<<<(total + 255) / 256, 256, 0, stream>>>(pts, out);
}

// Round 5
// 87.937 us; speedup vs baseline: 1.7642x; 1.0641x over previous
//
#include <hip/hip_runtime.h>

#define BB 4
#define HH 480
#define WW 640

// det of general 3x3
__device__ __forceinline__ double det3d(double a, double b, double c,
                                        double d, double e, double f,
                                        double g, double h, double i) {
    return a * (e * i - f * h) - b * (d * i - f * g) + c * (d * h - e * g);
}

// det of symmetric 3x3 [[a,b,c],[b,e,f],[c,f,i]]
__device__ __forceinline__ double sdet3d(double a, double b, double c,
                                         double e, double f, double i) {
    return a * (e * i - f * f) + b * (2.0 * c * f - b * i) - c * c * e;
}

// fast f64 reciprocal: f32 seed + 1 Newton step (rel err ~1e-14)
__device__ __forceinline__ double frcp(double d) {
    float rf = __builtin_amdgcn_rcpf((float)d);
    double r = (double)rf;
    r = r * __builtin_fma(-d, r, 2.0);
    return r;
}

__global__ __launch_bounds__(256) void d2n_kernel(const float* __restrict__ pts,
                                                  float* __restrict__ out) {
    int idx = blockIdx.x * 256 + threadIdx.x;
    if (idx >= BB * HH * WW) return;
    int x = idx % WW;
    int t1 = idx / WW;
    int y = t1 % HH;
    int b = t1 / HH;

    const size_t HW = (size_t)HH * WW;
    const float* xs = pts + ((size_t)b * 3 + 0) * HW;
    const float* ys = pts + ((size_t)b * 3 + 1) * HW;
    const float* zs = pts + ((size_t)b * 3 + 2) * HW;

    // ---- Branch-free stencil: clamped addresses, all 27 loads in flight ----
    int row[3], col[3];
    bool rin[3], cin[3];
#pragma unroll
    for (int k = 0; k < 3; ++k) {
        int yy = y + k - 1, xx = x + k - 1;
        rin[k] = (unsigned)yy < HH;
        cin[k] = (unsigned)xx < WW;
        row[k] = min(max(yy, 0), HH - 1) * WW;
        col[k] = min(max(xx, 0), WW - 1);
    }
    float px[9], py[9], pz[9];
    bool inb[9];
#pragma unroll
    for (int i = 0; i < 9; ++i) {
        int r = i / 3, c = i % 3;
        int o = row[r] + col[c];
        inb[i] = rin[r] & cin[c];
        pz[i] = zs[o];
        px[i] = xs[o];
        py[i] = ys[o];
    }

    // ---- Gram accumulation (f32, matches reference AtA precision) ----
    float sxx = 0.f, sxy = 0.f, sxz = 0.f, sx = 0.f;
    float syy = 0.f, syz = 0.f, sy = 0.f;
    float szz = 0.f, sz = 0.f, cnt = 0.f;
#pragma unroll
    for (int i = 0; i < 9; ++i) {
        float w = (inb[i] && pz[i] > 0.0f && pz[i] < 10.0f) ? 1.0f : 0.0f;
        float qx = px[i] * w, qy = py[i] * w, qz = pz[i] * w;
        sxx += qx * px[i]; sxy += qx * py[i]; sxz += qx * pz[i]; sx += qx;
        syy += qy * py[i]; syz += qy * pz[i]; sy += qy;
        szz += qz * pz[i]; sz += qz;
        cnt += w;
    }

    // ---- Promote to f64; scale by 1/trace so eigenvalues land in [0,1] ----
    double tr = (double)sxx + (double)syy + (double)szz + (double)cnt;
    double it = frcp(tr);
    double m00 = sxx * it, m01 = sxy * it, m02 = sxz * it, m03 = sx * it;
    double m11 = syy * it, m12 = syz * it, m13 = sy * it;
    double m22 = szz * it, m23 = sz * it, m33 = cnt * it;

    // ---- Characteristic polynomial p(l)=l^4 - e1 l^3 + e2 l^2 - e3 l + e4 ----
    double e1 = m00 + m11 + m22 + m33;
    double e2 = (m00 * m11 - m01 * m01) + (m00 * m22 - m02 * m02) +
                (m00 * m33 - m03 * m03) + (m11 * m22 - m12 * m12) +
                (m11 * m33 - m13 * m13) + (m22 * m33 - m23 * m23);
    // principal 3x3 minors (symmetric)
    double P0 = sdet3d(m11, m12, m13, m22, m23, m33);
    double P1 = sdet3d(m00, m02, m03, m22, m23, m33);
    double P2 = sdet3d(m00, m01, m03, m11, m13, m33);
    double P3 = sdet3d(m00, m01, m02, m11, m12, m22);
    double e3 = P0 + P1 + P2 + P3;
    double e4 = m00 * P0
              - m01 * det3d(m01, m12, m13, m02, m22, m23, m03, m23, m33)
              + m02 * det3d(m01, m11, m13, m02, m12, m23, m03, m13, m33)
              - m03 * det3d(m01, m11, m12, m02, m12, m22, m03, m13, m23);

    // ---- Newton from 0 toward smallest eigenvalue (monotone: p>0, p'<0) ----
    double t31 = 3.0 * e1, t22 = 2.0 * e2;
    double lam = 0.0;
#pragma unroll
    for (int itn = 0; itn < 14; ++itn) {
        double p  = (((lam - e1) * lam + e2) * lam - e3) * lam + e4;
        double dp = ((4.0 * lam - t31) * lam + t22) * lam - e3;
        dp = fmin(dp, -1e-30);
        lam = lam - p * frcp(dp);
        lam = fmin(fmax(lam, 0.0), 0.26);
    }

    // ---- Adjugate of (M - lam I): rank-1 = c * v1 v1^T at converged lam ----
    double d0 = m00 - lam, d1 = m11 - lam, d2 = m22 - lam, d3 = m33 - lam;
    double C00 =  sdet3d(d1, m12, m13, d2, m23, d3);
    double C11 =  sdet3d(d0, m02, m03, d2, m23, d3);
    double C22 =  sdet3d(d0, m01, m03, d1, m13, d3);
    double C33 =  sdet3d(d0, m01, m02, d1, m12, d2);
    double C01 = -det3d(m01, m12, m13, m02, d2, m23, m03, m23, d3);
    double C02 =  det3d(m01, d1, m13, m02, m12, m23, m03, m13, d3);
    double C03 = -det3d(m01, d1, m12, m02, m12, d2, m03, m13, m23);
    double C12 = -det3d(d0, m01, m03, m02, m12, m23, m03, m13, d3);
    double C13 =  det3d(d0, m01, m02, m02, m12, d2, m03, m13, m23);
    double C23 = -det3d(d0, m01, m02, m01, d1, m12, m03, m13, m23);

    // pick column with largest |diagonal cofactor| (= largest v1 comp^2);
    // that diagonal entry is also the max-|.| component of its column.
    double best = fabs(C00);
    double vx = C00, vy = C01, vz = C02, vd = C00;
    double a1 = fabs(C11);
    if (a1 > best) { best = a1; vx = C01; vy = C11; vz = C12; vd = C11; }
    double a2 = fabs(C22);
    if (a2 > best) { best = a2; vx = C02; vy = C12; vz = C22; vd = C22; }
    double a3 = fabs(C33);
    if (a3 > best) { best = a3; vx = C03; vy = C13; vz = C23; vd = C33; }

    // scale column to [-1,1] (j-th comp -> 1), then finish in f32
    double sc = frcp(vd);
    float fx = (float)(vx * sc), fy = (float)(vy * sc), fz = (float)(vz * sc);
    // note: 4th comp scales to 1 but is not needed for the output

    float nd = fx * fx + fy * fy + fz * fz;
    float inv = __builtin_amdgcn_rsqf(fmaxf(nd, 1e-30f));
    float nx = fx * inv, ny = fy * inv, nz = fz * inv;

    int o = y * WW + x;
    float cx = px[4], cy = py[4], cz = pz[4];
    float dot = nx * cx + ny * cy + nz * cz;
    float sgn = (dot > 0.0f) ? 1.0f : ((dot < 0.0f) ? -1.0f : 0.0f);
    nx *= sgn; ny *= sgn; nz *= sgn;

    out[((size_t)b * 3 + 0) * HW + o] = nx;
    out[((size_t)b * 3 + 1) * HW + o] = ny;
    out[((size_t)b * 3 + 2) * HW + o] = nz;

    bool cvalid = (cz > 0.0f && cz < 10.0f);
    bool m = cvalid && (cnt >= 4.0f) && (nx * nx + ny * ny + nz * nz > 0.25f);
    out[(size_t)BB * 3 * HW + (size_t)b * HW + o] = m ? 1.0f : 0.0f;
}

extern "C" void kernel_launch(void* const* d_in, const int* in_sizes, int n_in,
                              void* d_out, int out_size, void* d_ws, size_t ws_size,
                              hipStream_t stream) {
    const float* pts = (const float*)d_in[0];
    float* out = (float*)d_out;
    int total = BB * HH * WW;
    d2n_kernel<<<(total + 255) / 256, 256, 0, stream>>>(pts, out);
}

// Round 6
// 85.505 us; speedup vs baseline: 1.8143x; 1.0284x over previous
//
#include <hip/hip_runtime.h>

#define BB 4
#define HH 480
#define WW 640

// det of general 3x3
__device__ __forceinline__ double det3d(double a, double b, double c,
                                        double d, double e, double f,
                                        double g, double h, double i) {
    return a * (e * i - f * h) - b * (d * i - f * g) + c * (d * h - e * g);
}

// det of symmetric 3x3 [[a,b,c],[b,e,f],[c,f,i]]
__device__ __forceinline__ double sdet3d(double a, double b, double c,
                                         double e, double f, double i) {
    return a * (e * i - f * f) + b * (2.0 * c * f - b * i) - c * c * e;
}

// cheap reciprocal of a double: f32 seed, ~1e-5 relative error.
// Valid where the use is scale-invariant or self-correcting (Newton).
__device__ __forceinline__ double crcp(double d) {
    return (double)__builtin_amdgcn_rcpf((float)d);
}

__global__ __launch_bounds__(256) void d2n_kernel(const float* __restrict__ pts,
                                                  float* __restrict__ out) {
    int idx = blockIdx.x * 256 + threadIdx.x;
    if (idx >= BB * HH * WW) return;
    int x = idx % WW;
    int t1 = idx / WW;
    int y = t1 % HH;
    int b = t1 / HH;

    const size_t HW = (size_t)HH * WW;
    const float* xs = pts + ((size_t)b * 3 + 0) * HW;
    const float* ys = pts + ((size_t)b * 3 + 1) * HW;
    const float* zs = pts + ((size_t)b * 3 + 2) * HW;

    // ---- Branch-free stencil: clamped addresses, all 27 loads in flight ----
    int row[3], col[3];
    bool rin[3], cin[3];
#pragma unroll
    for (int k = 0; k < 3; ++k) {
        int yy = y + k - 1, xx = x + k - 1;
        rin[k] = (unsigned)yy < HH;
        cin[k] = (unsigned)xx < WW;
        row[k] = min(max(yy, 0), HH - 1) * WW;
        col[k] = min(max(xx, 0), WW - 1);
    }
    float px[9], py[9], pz[9];
    bool inb[9];
#pragma unroll
    for (int i = 0; i < 9; ++i) {
        int r = i / 3, c = i % 3;
        int o = row[r] + col[c];
        inb[i] = rin[r] & cin[c];
        pz[i] = zs[o];
        px[i] = xs[o];
        py[i] = ys[o];
    }

    // ---- Gram accumulation (f32, matches reference AtA precision) ----
    float sxx = 0.f, sxy = 0.f, sxz = 0.f, sx = 0.f;
    float syy = 0.f, syz = 0.f, sy = 0.f;
    float szz = 0.f, sz = 0.f, cnt = 0.f;
#pragma unroll
    for (int i = 0; i < 9; ++i) {
        float w = (inb[i] && pz[i] > 0.0f && pz[i] < 10.0f) ? 1.0f : 0.0f;
        float qx = px[i] * w, qy = py[i] * w, qz = pz[i] * w;
        sxx += qx * px[i]; sxy += qx * py[i]; sxz += qx * pz[i]; sx += qx;
        syy += qy * py[i]; syz += qy * pz[i]; sy += qy;
        szz += qz * pz[i]; sz += qz;
        cnt += w;
    }

    // ---- Promote to f64; scale by ~1/trace (uniform scale: eigvec-invariant,
    //      so a 1e-5-accurate reciprocal is exactly as good as a perfect one) ----
    double tr = (double)sxx + (double)syy + (double)szz + (double)cnt;
    double it = crcp(tr);
    double m00 = sxx * it, m01 = sxy * it, m02 = sxz * it, m03 = sx * it;
    double m11 = syy * it, m12 = syz * it, m13 = sy * it;
    double m22 = szz * it, m23 = sz * it, m33 = cnt * it;

    // ---- Characteristic polynomial p(l)=l^4 - e1 l^3 + e2 l^2 - e3 l + e4
    //      (f64: coefficients are differences of products -> cancellation) ----
    double e1 = m00 + m11 + m22 + m33;
    double e2 = (m00 * m11 - m01 * m01) + (m00 * m22 - m02 * m02) +
                (m00 * m33 - m03 * m03) + (m11 * m22 - m12 * m12) +
                (m11 * m33 - m13 * m13) + (m22 * m33 - m23 * m23);
    double P0 = sdet3d(m11, m12, m13, m22, m23, m33);
    double P1 = sdet3d(m00, m02, m03, m22, m23, m33);
    double P2 = sdet3d(m00, m01, m03, m11, m13, m33);
    double P3 = sdet3d(m00, m01, m02, m11, m12, m22);
    double e3 = P0 + P1 + P2 + P3;
    double e4 = m00 * P0
              - m01 * det3d(m01, m12, m13, m02, m22, m23, m03, m23, m33)
              + m02 * det3d(m01, m11, m13, m02, m12, m23, m03, m13, m33)
              - m03 * det3d(m01, m11, m12, m02, m12, m22, m03, m13, m23);

    // ---- Newton toward smallest eigenvalue: 8 f32 warm iters + 5 f64 polish.
    //      From lam=0: p>0, p'<0 -> monotone. Slight f32 overshoot into
    //      (mu1, c1) has p<0 with clamped-negative p', stepping back left. ----
    float e1f = (float)e1, e2f = (float)e2, e3f = (float)e3, e4f = (float)e4;
    float t31f = 3.0f * e1f, t22f = 2.0f * e2f;
    float lf = 0.0f;
#pragma unroll
    for (int itn = 0; itn < 8; ++itn) {
        float p  = (((lf - e1f) * lf + e2f) * lf - e3f) * lf + e4f;
        float dp = ((4.0f * lf - t31f) * lf + t22f) * lf - e3f;
        dp = fminf(dp, -1e-30f);
        lf = lf - p * __builtin_amdgcn_rcpf(dp);
        lf = fminf(fmaxf(lf, 0.0f), 0.26f);
    }
    double t31 = 3.0 * e1, t22 = 2.0 * e2;
    double lam = (double)lf;
#pragma unroll
    for (int itn = 0; itn < 5; ++itn) {
        double p  = (((lam - e1) * lam + e2) * lam - e3) * lam + e4;
        double dp = ((4.0 * lam - t31) * lam + t22) * lam - e3;
        dp = fmin(dp, -1e-30);
        lam = lam - p * crcp(dp);  // 1e-5-accurate step: self-correcting
        lam = fmin(fmax(lam, 0.0), 0.26);
    }

    // ---- Adjugate of (M - lam I): rank-1 = c * v1 v1^T at converged lam ----
    double d0 = m00 - lam, d1 = m11 - lam, d2 = m22 - lam, d3 = m33 - lam;
    double C00 =  sdet3d(d1, m12, m13, d2, m23, d3);
    double C11 =  sdet3d(d0, m02, m03, d2, m23, d3);
    double C22 =  sdet3d(d0, m01, m03, d1, m13, d3);
    double C33 =  sdet3d(d0, m01, m02, d1, m12, d2);
    double C01 = -det3d(m01, m12, m13, m02, d2, m23, m03, m23, d3);
    double C02 =  det3d(m01, d1, m13, m02, m12, m23, m03, m13, d3);
    double C03 = -det3d(m01, d1, m12, m02, m12, d2, m03, m13, m23);
    double C12 = -det3d(d0, m01, m03, m02, m12, m23, m03, m13, d3);
    double C13 =  det3d(d0, m01, m02, m02, m12, d2, m03, m13, m23);
    double C23 = -det3d(d0, m01, m02, m01, d1, m12, m03, m13, m23);

    // pick column with largest |diagonal cofactor| (= largest v1 comp^2)
    double best = fabs(C00);
    double vx = C00, vy = C01, vz = C02, vd = C00;
    double a1 = fabs(C11);
    if (a1 > best) { best = a1; vx = C01; vy = C11; vz = C12; vd = C11; }
    double a2 = fabs(C22);
    if (a2 > best) { best = a2; vx = C02; vy = C12; vz = C22; vd = C22; }
    double a3 = fabs(C33);
    if (a3 > best) { best = a3; vx = C03; vy = C13; vz = C23; vd = C33; }

    // scale column by ~1/vd (uniform scale of the eigvec: error cancels in
    // the f32 normalization below), then finish in f32
    double sc = crcp(vd);
    float fx = (float)(vx * sc), fy = (float)(vy * sc), fz = (float)(vz * sc);

    float nd = fx * fx + fy * fy + fz * fz;
    float inv = __builtin_amdgcn_rsqf(fmaxf(nd, 1e-30f));
    float nx = fx * inv, ny = fy * inv, nz = fz * inv;

    int o = y * WW + x;
    float cx = px[4], cy = py[4], cz = pz[4];
    float dot = nx * cx + ny * cy + nz * cz;
    float sgn = (dot > 0.0f) ? 1.0f : ((dot < 0.0f) ? -1.0f : 0.0f);
    nx *= sgn; ny *= sgn; nz *= sgn;

    out[((size_t)b * 3 + 0) * HW + o] = nx;
    out[((size_t)b * 3 + 1) * HW + o] = ny;
    out[((size_t)b * 3 + 2) * HW + o] = nz;

    bool cvalid = (cz > 0.0f && cz < 10.0f);
    bool m = cvalid && (cnt >= 4.0f) && (nx * nx + ny * ny + nz * nz > 0.25f);
    out[(size_t)BB * 3 * HW + (size_t)b * HW + o] = m ? 1.0f : 0.0f;
}

extern "C" void kernel_launch(void* const* d_in, const int* in_sizes, int n_in,
                              void* d_out, int out_size, void* d_ws, size_t ws_size,
                              hipStream_t stream) {
    const float* pts = (const float*)d_in[0];
    float* out = (float*)d_out;
    int total = BB * HH * WW;
    d2n_kernel<<<(total + 255) / 256, 256, 0, stream>>>(pts, out);
}